// Round 4
// baseline (1341.108 us; speedup 1.0000x reference)
//
#include <hip/hip_runtime.h>

#define NUM_USER  200000
#define NUM_GROUP 50000
#define NN        (NUM_USER + NUM_GROUP)   // 250000
#define E_EDGES   4000000
#define D         64
#define B         8192

#define SCAN_CHUNK   1024                                   // counts per block
#define SCAN_BLOCKS  ((NN + SCAN_CHUNK - 1) / SCAN_CHUNK)   // 245

#define BSHIFT       10                                     // 1024 rows / bucket
#define NB_BUCKETS   ((NN + (1 << BSHIFT) - 1) >> BSHIFT)   // 245
#define CHUNK_EDGES  8192                                   // edges per phase-A block

// ---------------------------------------------------------------------------
// CSR build step 1: histogram of destination rows
// ---------------------------------------------------------------------------
__global__ void __launch_bounds__(256)
hist_kernel(const int* __restrict__ rows, int* __restrict__ counts) {
    int e = blockIdx.x * blockDim.x + threadIdx.x;
    if (e >= E_EDGES) return;
    atomicAdd(&counts[rows[e]], 1);
}

// ---------------------------------------------------------------------------
// Scan pass A: per-block sums of 1024 counts each
// ---------------------------------------------------------------------------
__global__ void __launch_bounds__(256)
scan_blocksums(const int* __restrict__ counts, int* __restrict__ blockSums) {
    __shared__ int red[256];
    const int t = threadIdx.x;
    const int base = blockIdx.x * SCAN_CHUNK + t * 4;
    int s = 0;
    #pragma unroll
    for (int k = 0; k < 4; ++k) {
        int i = base + k;
        if (i < NN) s += counts[i];
    }
    red[t] = s;
    __syncthreads();
    for (int off = 128; off > 0; off >>= 1) {
        if (t < off) red[t] += red[t + off];
        __syncthreads();
    }
    if (t == 0) blockSums[blockIdx.x] = red[0];
}

// ---------------------------------------------------------------------------
// Scan pass B: exclusive scan of the 245 block sums (single small block)
// ---------------------------------------------------------------------------
__global__ void __launch_bounds__(256)
scan_offsets(const int* __restrict__ blockSums,
             int* __restrict__ blockOffs,
             int* __restrict__ row_ptr) {
    __shared__ int s[256];
    const int t = threadIdx.x;
    int v = (t < SCAN_BLOCKS) ? blockSums[t] : 0;
    s[t] = v;
    __syncthreads();
    for (int off = 1; off < 256; off <<= 1) {
        int u = (t >= off) ? s[t - off] : 0;
        __syncthreads();
        s[t] += u;
        __syncthreads();
    }
    if (t < SCAN_BLOCKS) blockOffs[t] = s[t] - v;   // exclusive
    if (t == 255) row_ptr[NN] = s[255];             // grand total = E
}

// ---------------------------------------------------------------------------
// Scan pass C: intra-block exclusive scan + global offset -> row_ptr
// ---------------------------------------------------------------------------
__global__ void __launch_bounds__(256)
scan_final(const int* __restrict__ counts,
           const int* __restrict__ blockOffs,
           int* __restrict__ row_ptr) {
    __shared__ int s[256];
    const int t = threadIdx.x;
    const int base = blockIdx.x * SCAN_CHUNK + t * 4;
    int c0 = 0, c1 = 0, c2 = 0, c3 = 0;
    if (base + 0 < NN) c0 = counts[base + 0];
    if (base + 1 < NN) c1 = counts[base + 1];
    if (base + 2 < NN) c2 = counts[base + 2];
    if (base + 3 < NN) c3 = counts[base + 3];
    int tsum = c0 + c1 + c2 + c3;
    s[t] = tsum;
    __syncthreads();
    for (int off = 1; off < 256; off <<= 1) {
        int u = (t >= off) ? s[t - off] : 0;
        __syncthreads();
        s[t] += u;
        __syncthreads();
    }
    int run = blockOffs[blockIdx.x] + s[t] - tsum;   // exclusive prefix
    int p0 = run;
    int p1 = p0 + c0;
    int p2 = p1 + c1;
    int p3 = p2 + c2;
    if (base + 0 < NN) row_ptr[base + 0] = p0;
    if (base + 1 < NN) row_ptr[base + 1] = p1;
    if (base + 2 < NN) row_ptr[base + 2] = p2;
    if (base + 3 < NN) row_ptr[base + 3] = p3;
}

// ---------------------------------------------------------------------------
// Bucket cursors for phase A: staging region base = CSR base of the bucket
// ---------------------------------------------------------------------------
__global__ void __launch_bounds__(256)
init_bucket_cursors(const int* __restrict__ row_ptr, int* __restrict__ cursorA) {
    int b = blockIdx.x * blockDim.x + threadIdx.x;
    if (b < NB_BUCKETS) cursorA[b] = row_ptr[b << BSHIFT];
}

// ---------------------------------------------------------------------------
// Phase A: LDS-aggregated bucket append.
// Each block bins CHUNK_EDGES edges into NB_BUCKETS in LDS, then copies each
// bucket's contiguous run to global staging (one atomic per run, coalesced).
// Staged element: { (row_in_bucket << 18) | col, bits(val) }.
// ---------------------------------------------------------------------------
__global__ void __launch_bounds__(256)
bucket_phaseA(const int*   __restrict__ rows,
              const int*   __restrict__ cols,
              const float* __restrict__ vals,
              int*         __restrict__ cursorA,
              int2*        __restrict__ stage) {
    __shared__ int  cnt[256];
    __shared__ int  off[256];
    __shared__ int  cur[256];
    __shared__ int2 stg[CHUNK_EDGES];    // 64 KB
    const int t = threadIdx.x;
    cnt[t] = 0;
    __syncthreads();

    const int base = blockIdx.x * CHUNK_EDGES;
    #pragma unroll
    for (int k = 0; k < CHUNK_EDGES / 256; ++k) {
        int e = base + t + k * 256;
        if (e < E_EDGES) atomicAdd(&cnt[rows[e] >> BSHIFT], 1);
    }
    __syncthreads();

    // exclusive scan of cnt -> off (Hillis-Steele over 256)
    int v = cnt[t];
    off[t] = v;
    __syncthreads();
    for (int o = 1; o < 256; o <<= 1) {
        int u = (t >= o) ? off[t - o] : 0;
        __syncthreads();
        off[t] += u;
        __syncthreads();
    }
    int excl = off[t] - v;
    __syncthreads();
    off[t] = excl;
    cur[t] = excl;
    __syncthreads();

    // place into LDS staging
    #pragma unroll
    for (int k = 0; k < CHUNK_EDGES / 256; ++k) {
        int e = base + t + k * 256;
        if (e < E_EDGES) {
            int r = rows[e];
            int b = r >> BSHIFT;
            int slot = atomicAdd(&cur[b], 1);
            stg[slot] = make_int2(((r & ((1 << BSHIFT) - 1)) << 18) | cols[e],
                                  __float_as_int(vals[e]));
        }
    }
    __syncthreads();

    // copy runs out: wave w handles buckets w, w+4, ...
    const int wave = t >> 6, lane = t & 63;
    for (int b = wave; b < NB_BUCKETS; b += 4) {
        int n = cnt[b];
        if (n == 0) continue;
        int gb;
        if (lane == 0) gb = atomicAdd(&cursorA[b], n);
        gb = __shfl(gb, 0, 64);
        int lbase = off[b];
        for (int i = lane; i < n; i += 64)
            stage[gb + i] = stg[lbase + i];
    }
}

// ---------------------------------------------------------------------------
// Phase B: exact CSR placement, ONE block per bucket (single-XCD write region
// of 128 KB -> full cache lines). LDS cursors per row.
// ---------------------------------------------------------------------------
__global__ void __launch_bounds__(256)
bucket_phaseB(const int*  __restrict__ row_ptr,
              const int2* __restrict__ stage,
              int2*       __restrict__ pairs) {
    __shared__ int curs[1 << BSHIFT];    // 1024 row cursors
    const int b = blockIdx.x;
    const int rowBase = b << BSHIFT;
    const int nRows = (NN - rowBase < (1 << BSHIFT)) ? (NN - rowBase) : (1 << BSHIFT);
    const int t = threadIdx.x;
    for (int i = t; i < nRows; i += 256) curs[i] = row_ptr[rowBase + i];
    __syncthreads();
    const int s = row_ptr[rowBase];
    const int e = row_ptr[(rowBase + (1 << BSHIFT) < NN) ? rowBase + (1 << BSHIFT) : NN];
    for (int i = s + t; i < e; i += 256) {
        int2 p = stage[i];
        int rib = p.x >> 18;
        int col = p.x & 0x3FFFF;
        int slot = atomicAdd(&curs[rib], 1);
        pairs[slot] = make_int2(col, p.y);
    }
}

// ---------------------------------------------------------------------------
// Pull-mode SpMM: one wave per destination row, lane = dim.
// ---------------------------------------------------------------------------
template <bool FIRST>
__global__ void __launch_bounds__(256)
spmm_pull(const int*  __restrict__ row_ptr,
          const int2* __restrict__ pairs,
          const float* __restrict__ ut,
          const float* __restrict__ gt,
          const float* __restrict__ x,
          float*       __restrict__ y) {
    int row  = blockIdx.x * 4 + (threadIdx.x >> 6);   // 4 waves / block
    int lane = threadIdx.x & 63;
    if (row >= NN) return;
    int start = row_ptr[row];
    int end   = row_ptr[row + 1];

    auto loadx = [&](int c) -> float {
        if (FIRST) {
            return (c < NUM_USER) ? ut[(size_t)c * D + lane]
                                  : gt[(size_t)(c - NUM_USER) * D + lane];
        } else {
            return x[(size_t)c * D + lane];
        }
    };

    float acc = 0.f;
    int e = start;
    for (; e + 4 <= end; e += 4) {
        int2 p0 = pairs[e + 0];
        int2 p1 = pairs[e + 1];
        int2 p2 = pairs[e + 2];
        int2 p3 = pairs[e + 3];
        float x0 = loadx(p0.x);
        float x1 = loadx(p1.x);
        float x2 = loadx(p2.x);
        float x3 = loadx(p3.x);
        acc += __int_as_float(p0.y) * x0;
        acc += __int_as_float(p1.y) * x1;
        acc += __int_as_float(p2.y) * x2;
        acc += __int_as_float(p3.y) * x3;
    }
    for (; e < end; ++e) {
        int2 p = pairs[e];
        acc += __int_as_float(p.y) * loadx(p.x);
    }
    y[(size_t)row * D + lane] = acc;
}

// ---------------------------------------------------------------------------
// Output init: raw table gathers (outputs 3..5) and the level-0 contribution
// ---------------------------------------------------------------------------
__global__ void gather_init(const float* __restrict__ ut,
                            const float* __restrict__ gt,
                            const int*   __restrict__ ui,
                            const int*   __restrict__ pg,
                            const int*   __restrict__ ng,
                            float*       __restrict__ out) {
    int i = blockIdx.x * blockDim.x + threadIdx.x;    // B*D threads
    if (i >= B * D) return;
    int b = i >> 6, d = i & 63;
    float u = ut[(size_t)ui[b] * D + d];
    float p = gt[(size_t)pg[b] * D + d];
    float n = gt[(size_t)ng[b] * D + d];
    const int S = B * D;
    out[0 * S + i] = 0.25f * u;
    out[1 * S + i] = 0.25f * p;
    out[2 * S + i] = 0.25f * n;
    out[3 * S + i] = u;
    out[4 * S + i] = p;
    out[5 * S + i] = n;
}

// ---------------------------------------------------------------------------
// Per-level accumulation of 0.25 * emb_l at the gathered rows
// ---------------------------------------------------------------------------
__global__ void gather_acc(const float* __restrict__ emb,
                           const int*   __restrict__ ui,
                           const int*   __restrict__ pg,
                           const int*   __restrict__ ng,
                           float*       __restrict__ out) {
    int i = blockIdx.x * blockDim.x + threadIdx.x;    // B*D threads
    if (i >= B * D) return;
    int b = i >> 6, d = i & 63;
    const int S = B * D;
    out[0 * S + i] += 0.25f * emb[(size_t)ui[b] * D + d];
    out[1 * S + i] += 0.25f * emb[((size_t)NUM_USER + pg[b]) * D + d];
    out[2 * S + i] += 0.25f * emb[((size_t)NUM_USER + ng[b]) * D + d];
}

// ---------------------------------------------------------------------------
extern "C" void kernel_launch(void* const* d_in, const int* in_sizes, int n_in,
                              void* d_out, int out_size, void* d_ws, size_t ws_size,
                              hipStream_t stream) {
    const float* ut   = (const float*)d_in[0];
    const float* gt   = (const float*)d_in[1];
    const float* vals = (const float*)d_in[2];
    const int*   rows = (const int*)d_in[3];
    const int*   cols = (const int*)d_in[4];
    const int*   ui   = (const int*)d_in[5];
    const int*   pg   = (const int*)d_in[6];
    const int*   ng   = (const int*)d_in[7];
    float* out = (float*)d_out;

    // --- workspace layout ---
    char* ws = (char*)d_ws;
    float* emb_a   = (float*)ws;   ws += (size_t)NN * D * sizeof(float);   // 64 MB
    float* emb_b   = (float*)ws;   ws += (size_t)NN * D * sizeof(float);   // 64 MB
    int2*  pairs   = (int2*)ws;    ws += (size_t)E_EDGES * sizeof(int2);   // 32 MB
    int*   row_ptr = (int*)ws;     ws += (size_t)(NN + 1) * sizeof(int);
    int*   counts  = (int*)ws;     ws += (size_t)NN * sizeof(int);
    int*   blockSums = (int*)ws;   ws += (size_t)SCAN_BLOCKS * sizeof(int);
    int*   blockOffs = (int*)ws;   ws += (size_t)SCAN_BLOCKS * sizeof(int);
    int*   cursorA   = (int*)ws;   ws += (size_t)NB_BUCKETS * sizeof(int);
    // phase-A staging aliases emb_b (dead until SpMM level 2)
    int2* stage = (int2*)emb_b;                                            // 32 MB

    // --- CSR build (once per call; reused for all 3 levels) ---
    hipMemsetAsync(counts, 0, (size_t)NN * sizeof(int), stream);
    hist_kernel<<<(E_EDGES + 255) / 256, 256, 0, stream>>>(rows, counts);
    scan_blocksums<<<SCAN_BLOCKS, 256, 0, stream>>>(counts, blockSums);
    scan_offsets<<<1, 256, 0, stream>>>(blockSums, blockOffs, row_ptr);
    scan_final<<<SCAN_BLOCKS, 256, 0, stream>>>(counts, blockOffs, row_ptr);
    init_bucket_cursors<<<1, 256, 0, stream>>>(row_ptr, cursorA);
    bucket_phaseA<<<(E_EDGES + CHUNK_EDGES - 1) / CHUNK_EDGES, 256, 0, stream>>>(
        rows, cols, vals, cursorA, stage);
    bucket_phaseB<<<NB_BUCKETS, 256, 0, stream>>>(row_ptr, stage, pairs);

    // --- outputs 3..5 + level-0 contribution ---
    gather_init<<<(B * D + 255) / 256, 256, 0, stream>>>(ut, gt, ui, pg, ng, out);

    // --- 3 propagation levels, pull mode ---
    const int spmmBlocks = (NN + 3) / 4;   // 4 rows (waves) per 256-thread block
    spmm_pull<true><<<spmmBlocks, 256, 0, stream>>>(row_ptr, pairs, ut, gt, nullptr, emb_a);
    gather_acc<<<(B * D + 255) / 256, 256, 0, stream>>>(emb_a, ui, pg, ng, out);

    spmm_pull<false><<<spmmBlocks, 256, 0, stream>>>(row_ptr, pairs, ut, gt, emb_a, emb_b);
    gather_acc<<<(B * D + 255) / 256, 256, 0, stream>>>(emb_b, ui, pg, ng, out);

    spmm_pull<false><<<spmmBlocks, 256, 0, stream>>>(row_ptr, pairs, ut, gt, emb_b, emb_a);
    gather_acc<<<(B * D + 255) / 256, 256, 0, stream>>>(emb_a, ui, pg, ng, out);
}

// Round 5
// 1178.501 us; speedup vs baseline: 1.1380x; 1.1380x over previous
//
#include <hip/hip_runtime.h>

#define NUM_USER  200000
#define NUM_GROUP 50000
#define NN        (NUM_USER + NUM_GROUP)   // 250000
#define E_EDGES   4000000
#define D         64
#define B         8192

#define SCAN_CHUNK   1024                                   // counts per block
#define SCAN_BLOCKS  ((NN + SCAN_CHUNK - 1) / SCAN_CHUNK)   // 245

#define BSHIFT       10                                     // 1024 rows / bucket
#define NB_BUCKETS   ((NN + (1 << BSHIFT) - 1) >> BSHIFT)   // 245
#define CHUNK_EDGES  4096                                   // edges per phase-A block

// ---------------------------------------------------------------------------
// CSR build step 1: histogram of destination rows
// ---------------------------------------------------------------------------
__global__ void __launch_bounds__(256)
hist_kernel(const int* __restrict__ rows, int* __restrict__ counts) {
    int e = blockIdx.x * blockDim.x + threadIdx.x;
    if (e >= E_EDGES) return;
    atomicAdd(&counts[rows[e]], 1);
}

// ---------------------------------------------------------------------------
// Scan pass A: per-block sums of 1024 counts each
// ---------------------------------------------------------------------------
__global__ void __launch_bounds__(256)
scan_blocksums(const int* __restrict__ counts, int* __restrict__ blockSums) {
    __shared__ int red[256];
    const int t = threadIdx.x;
    const int base = blockIdx.x * SCAN_CHUNK + t * 4;
    int s = 0;
    #pragma unroll
    for (int k = 0; k < 4; ++k) {
        int i = base + k;
        if (i < NN) s += counts[i];
    }
    red[t] = s;
    __syncthreads();
    for (int off = 128; off > 0; off >>= 1) {
        if (t < off) red[t] += red[t + off];
        __syncthreads();
    }
    if (t == 0) blockSums[blockIdx.x] = red[0];
}

// ---------------------------------------------------------------------------
// Scan pass B: exclusive scan of the 245 block sums (single small block)
// ---------------------------------------------------------------------------
__global__ void __launch_bounds__(256)
scan_offsets(const int* __restrict__ blockSums,
             int* __restrict__ blockOffs,
             int* __restrict__ row_ptr) {
    __shared__ int s[256];
    const int t = threadIdx.x;
    int v = (t < SCAN_BLOCKS) ? blockSums[t] : 0;
    s[t] = v;
    __syncthreads();
    for (int off = 1; off < 256; off <<= 1) {
        int u = (t >= off) ? s[t - off] : 0;
        __syncthreads();
        s[t] += u;
        __syncthreads();
    }
    if (t < SCAN_BLOCKS) blockOffs[t] = s[t] - v;   // exclusive
    if (t == 255) row_ptr[NN] = s[255];             // grand total = E
}

// ---------------------------------------------------------------------------
// Scan pass C: intra-block exclusive scan + global offset -> row_ptr
// ---------------------------------------------------------------------------
__global__ void __launch_bounds__(256)
scan_final(const int* __restrict__ counts,
           const int* __restrict__ blockOffs,
           int* __restrict__ row_ptr) {
    __shared__ int s[256];
    const int t = threadIdx.x;
    const int base = blockIdx.x * SCAN_CHUNK + t * 4;
    int c0 = 0, c1 = 0, c2 = 0, c3 = 0;
    if (base + 0 < NN) c0 = counts[base + 0];
    if (base + 1 < NN) c1 = counts[base + 1];
    if (base + 2 < NN) c2 = counts[base + 2];
    if (base + 3 < NN) c3 = counts[base + 3];
    int tsum = c0 + c1 + c2 + c3;
    s[t] = tsum;
    __syncthreads();
    for (int off = 1; off < 256; off <<= 1) {
        int u = (t >= off) ? s[t - off] : 0;
        __syncthreads();
        s[t] += u;
        __syncthreads();
    }
    int run = blockOffs[blockIdx.x] + s[t] - tsum;   // exclusive prefix
    int p0 = run;
    int p1 = p0 + c0;
    int p2 = p1 + c1;
    int p3 = p2 + c2;
    if (base + 0 < NN) row_ptr[base + 0] = p0;
    if (base + 1 < NN) row_ptr[base + 1] = p1;
    if (base + 2 < NN) row_ptr[base + 2] = p2;
    if (base + 3 < NN) row_ptr[base + 3] = p3;
}

// ---------------------------------------------------------------------------
// Bucket cursors for phase A: staging region base = CSR base of the bucket
// ---------------------------------------------------------------------------
__global__ void __launch_bounds__(256)
init_bucket_cursors(const int* __restrict__ row_ptr, int* __restrict__ cursorA) {
    int b = blockIdx.x * blockDim.x + threadIdx.x;
    if (b < NB_BUCKETS) cursorA[b] = row_ptr[b << BSHIFT];
}

// ---------------------------------------------------------------------------
// Phase A: LDS-aggregated bucket append.
// Each block bins CHUNK_EDGES edges into NB_BUCKETS in LDS, then copies each
// bucket's contiguous run to global staging (one atomic per run, coalesced).
// Copy-out order is ROTATED by blockIdx so concurrent blocks hit different
// bucket cursors (kills the round-4 convoy on cursorA atomics).
// Staged element: { (row_in_bucket << 18) | col, bits(val) }.
// ---------------------------------------------------------------------------
__global__ void __launch_bounds__(256)
bucket_phaseA(const int*   __restrict__ rows,
              const int*   __restrict__ cols,
              const float* __restrict__ vals,
              int*         __restrict__ cursorA,
              int2*        __restrict__ stage) {
    __shared__ int  cnt[256];
    __shared__ int  off[256];
    __shared__ int  cur[256];
    __shared__ int2 stg[CHUNK_EDGES];    // 32 KB
    const int t = threadIdx.x;
    cnt[t] = 0;
    __syncthreads();

    const int base = blockIdx.x * CHUNK_EDGES;
    #pragma unroll
    for (int k = 0; k < CHUNK_EDGES / 256; ++k) {
        int e = base + t + k * 256;
        if (e < E_EDGES) atomicAdd(&cnt[rows[e] >> BSHIFT], 1);
    }
    __syncthreads();

    // exclusive scan of cnt -> off (Hillis-Steele over 256)
    int v = cnt[t];
    off[t] = v;
    __syncthreads();
    for (int o = 1; o < 256; o <<= 1) {
        int u = (t >= o) ? off[t - o] : 0;
        __syncthreads();
        off[t] += u;
        __syncthreads();
    }
    int excl = off[t] - v;
    __syncthreads();
    off[t] = excl;
    cur[t] = excl;
    __syncthreads();

    // place into LDS staging
    #pragma unroll
    for (int k = 0; k < CHUNK_EDGES / 256; ++k) {
        int e = base + t + k * 256;
        if (e < E_EDGES) {
            int r = rows[e];
            int b = r >> BSHIFT;
            int slot = atomicAdd(&cur[b], 1);
            stg[slot] = make_int2(((r & ((1 << BSHIFT) - 1)) << 18) | cols[e],
                                  __float_as_int(vals[e]));
        }
    }
    __syncthreads();

    // copy runs out: wave w handles buckets {w, w+4, ...}, rotated by blockIdx
    const int wave = t >> 6, lane = t & 63;
    const int nb_w = (NB_BUCKETS - 1 - wave) / 4 + 1;   // buckets for this wave
    int rot = blockIdx.x % nb_w;
    for (int k = 0; k < nb_w; ++k) {
        int idx = k + rot; if (idx >= nb_w) idx -= nb_w;
        int b = wave + 4 * idx;
        int n = cnt[b];
        if (n == 0) continue;
        int gb;
        if (lane == 0) gb = atomicAdd(&cursorA[b], n);
        gb = __shfl(gb, 0, 64);
        int lbase = off[b];
        for (int i = lane; i < n; i += 64)
            stage[gb + i] = stg[lbase + i];
    }
}

// ---------------------------------------------------------------------------
// Phase B: exact CSR placement, ONE block per bucket (single-XCD write region
// of 128 KB -> full cache lines). LDS cursors per row.
// ---------------------------------------------------------------------------
__global__ void __launch_bounds__(256)
bucket_phaseB(const int*  __restrict__ row_ptr,
              const int2* __restrict__ stage,
              int2*       __restrict__ pairs) {
    __shared__ int curs[1 << BSHIFT];    // 1024 row cursors
    const int b = blockIdx.x;
    const int rowBase = b << BSHIFT;
    const int nRows = (NN - rowBase < (1 << BSHIFT)) ? (NN - rowBase) : (1 << BSHIFT);
    const int t = threadIdx.x;
    for (int i = t; i < nRows; i += 256) curs[i] = row_ptr[rowBase + i];
    __syncthreads();
    const int s = row_ptr[rowBase];
    const int e = row_ptr[(rowBase + (1 << BSHIFT) < NN) ? rowBase + (1 << BSHIFT) : NN];
    for (int i = s + t; i < e; i += 256) {
        int2 p = stage[i];
        int rib = p.x >> 18;
        int col = p.x & 0x3FFFF;
        int slot = atomicAdd(&curs[rib], 1);
        pairs[slot] = make_int2(col, p.y);
    }
}

// ---------------------------------------------------------------------------
// Pull-mode SpMM: one wave per destination row, lane = dim.
// ---------------------------------------------------------------------------
template <bool FIRST>
__global__ void __launch_bounds__(256)
spmm_pull(const int*  __restrict__ row_ptr,
          const int2* __restrict__ pairs,
          const float* __restrict__ ut,
          const float* __restrict__ gt,
          const float* __restrict__ x,
          float*       __restrict__ y) {
    int row  = blockIdx.x * 4 + (threadIdx.x >> 6);   // 4 waves / block
    int lane = threadIdx.x & 63;
    if (row >= NN) return;
    int start = row_ptr[row];
    int end   = row_ptr[row + 1];

    auto loadx = [&](int c) -> float {
        if (FIRST) {
            return (c < NUM_USER) ? ut[(size_t)c * D + lane]
                                  : gt[(size_t)(c - NUM_USER) * D + lane];
        } else {
            return x[(size_t)c * D + lane];
        }
    };

    float acc = 0.f;
    int e = start;
    for (; e + 4 <= end; e += 4) {
        int2 p0 = pairs[e + 0];
        int2 p1 = pairs[e + 1];
        int2 p2 = pairs[e + 2];
        int2 p3 = pairs[e + 3];
        float x0 = loadx(p0.x);
        float x1 = loadx(p1.x);
        float x2 = loadx(p2.x);
        float x3 = loadx(p3.x);
        acc += __int_as_float(p0.y) * x0;
        acc += __int_as_float(p1.y) * x1;
        acc += __int_as_float(p2.y) * x2;
        acc += __int_as_float(p3.y) * x3;
    }
    for (; e < end; ++e) {
        int2 p = pairs[e];
        acc += __int_as_float(p.y) * loadx(p.x);
    }
    y[(size_t)row * D + lane] = acc;
}

// ---------------------------------------------------------------------------
// Output init: raw table gathers (outputs 3..5) and the level-0 contribution
// ---------------------------------------------------------------------------
__global__ void gather_init(const float* __restrict__ ut,
                            const float* __restrict__ gt,
                            const int*   __restrict__ ui,
                            const int*   __restrict__ pg,
                            const int*   __restrict__ ng,
                            float*       __restrict__ out) {
    int i = blockIdx.x * blockDim.x + threadIdx.x;    // B*D threads
    if (i >= B * D) return;
    int b = i >> 6, d = i & 63;
    float u = ut[(size_t)ui[b] * D + d];
    float p = gt[(size_t)pg[b] * D + d];
    float n = gt[(size_t)ng[b] * D + d];
    const int S = B * D;
    out[0 * S + i] = 0.25f * u;
    out[1 * S + i] = 0.25f * p;
    out[2 * S + i] = 0.25f * n;
    out[3 * S + i] = u;
    out[4 * S + i] = p;
    out[5 * S + i] = n;
}

// ---------------------------------------------------------------------------
// Per-level accumulation of 0.25 * emb_l at the gathered rows
// ---------------------------------------------------------------------------
__global__ void gather_acc(const float* __restrict__ emb,
                           const int*   __restrict__ ui,
                           const int*   __restrict__ pg,
                           const int*   __restrict__ ng,
                           float*       __restrict__ out) {
    int i = blockIdx.x * blockDim.x + threadIdx.x;    // B*D threads
    if (i >= B * D) return;
    int b = i >> 6, d = i & 63;
    const int S = B * D;
    out[0 * S + i] += 0.25f * emb[(size_t)ui[b] * D + d];
    out[1 * S + i] += 0.25f * emb[((size_t)NUM_USER + pg[b]) * D + d];
    out[2 * S + i] += 0.25f * emb[((size_t)NUM_USER + ng[b]) * D + d];
}

// ---------------------------------------------------------------------------
extern "C" void kernel_launch(void* const* d_in, const int* in_sizes, int n_in,
                              void* d_out, int out_size, void* d_ws, size_t ws_size,
                              hipStream_t stream) {
    const float* ut   = (const float*)d_in[0];
    const float* gt   = (const float*)d_in[1];
    const float* vals = (const float*)d_in[2];
    const int*   rows = (const int*)d_in[3];
    const int*   cols = (const int*)d_in[4];
    const int*   ui   = (const int*)d_in[5];
    const int*   pg   = (const int*)d_in[6];
    const int*   ng   = (const int*)d_in[7];
    float* out = (float*)d_out;

    // --- workspace layout ---
    char* ws = (char*)d_ws;
    float* emb_a   = (float*)ws;   ws += (size_t)NN * D * sizeof(float);   // 64 MB
    float* emb_b   = (float*)ws;   ws += (size_t)NN * D * sizeof(float);   // 64 MB
    int2*  pairs   = (int2*)ws;    ws += (size_t)E_EDGES * sizeof(int2);   // 32 MB
    int*   row_ptr = (int*)ws;     ws += (size_t)(NN + 1) * sizeof(int);
    int*   counts  = (int*)ws;     ws += (size_t)NN * sizeof(int);
    int*   blockSums = (int*)ws;   ws += (size_t)SCAN_BLOCKS * sizeof(int);
    int*   blockOffs = (int*)ws;   ws += (size_t)SCAN_BLOCKS * sizeof(int);
    int*   cursorA   = (int*)ws;   ws += (size_t)NB_BUCKETS * sizeof(int);
    // phase-A staging aliases emb_b (dead until SpMM level 2)
    int2* stage = (int2*)emb_b;                                            // 32 MB

    // --- CSR build (once per call; reused for all 3 levels) ---
    hipMemsetAsync(counts, 0, (size_t)NN * sizeof(int), stream);
    hist_kernel<<<(E_EDGES + 255) / 256, 256, 0, stream>>>(rows, counts);
    scan_blocksums<<<SCAN_BLOCKS, 256, 0, stream>>>(counts, blockSums);
    scan_offsets<<<1, 256, 0, stream>>>(blockSums, blockOffs, row_ptr);
    scan_final<<<SCAN_BLOCKS, 256, 0, stream>>>(counts, blockOffs, row_ptr);
    init_bucket_cursors<<<1, 256, 0, stream>>>(row_ptr, cursorA);
    bucket_phaseA<<<(E_EDGES + CHUNK_EDGES - 1) / CHUNK_EDGES, 256, 0, stream>>>(
        rows, cols, vals, cursorA, stage);
    bucket_phaseB<<<NB_BUCKETS, 256, 0, stream>>>(row_ptr, stage, pairs);

    // --- outputs 3..5 + level-0 contribution ---
    gather_init<<<(B * D + 255) / 256, 256, 0, stream>>>(ut, gt, ui, pg, ng, out);

    // --- 3 propagation levels, pull mode ---
    const int spmmBlocks = (NN + 3) / 4;   // 4 rows (waves) per 256-thread block
    spmm_pull<true><<<spmmBlocks, 256, 0, stream>>>(row_ptr, pairs, ut, gt, nullptr, emb_a);
    gather_acc<<<(B * D + 255) / 256, 256, 0, stream>>>(emb_a, ui, pg, ng, out);

    spmm_pull<false><<<spmmBlocks, 256, 0, stream>>>(row_ptr, pairs, ut, gt, emb_a, emb_b);
    gather_acc<<<(B * D + 255) / 256, 256, 0, stream>>>(emb_b, ui, pg, ng, out);

    spmm_pull<false><<<spmmBlocks, 256, 0, stream>>>(row_ptr, pairs, ut, gt, emb_b, emb_a);
    gather_acc<<<(B * D + 255) / 256, 256, 0, stream>>>(emb_a, ui, pg, ng, out);
}

// Round 6
// 913.843 us; speedup vs baseline: 1.4675x; 1.2896x over previous
//
#include <hip/hip_runtime.h>

#define NUM_USER  200000
#define NUM_GROUP 50000
#define NN        (NUM_USER + NUM_GROUP)   // 250000
#define E_EDGES   4000000
#define D         64
#define B         8192

#define SCAN_CHUNK   1024                                   // counts per block
#define SCAN_BLOCKS  ((NN + SCAN_CHUNK - 1) / SCAN_CHUNK)   // 245

#define BSHIFT       10                                     // 1024 rows / bucket
#define NB_BUCKETS   ((NN + (1 << BSHIFT) - 1) >> BSHIFT)   // 245
#define CHUNK_EDGES  4096                                   // edges per phase-A block

// ---------------------------------------------------------------------------
// CSR build step 1: histogram of destination rows
// ---------------------------------------------------------------------------
__global__ void __launch_bounds__(256)
hist_kernel(const int* __restrict__ rows, int* __restrict__ counts) {
    int e = blockIdx.x * blockDim.x + threadIdx.x;
    if (e >= E_EDGES) return;
    atomicAdd(&counts[rows[e]], 1);
}

// ---------------------------------------------------------------------------
// Scan pass A: per-block sums of 1024 counts each
// ---------------------------------------------------------------------------
__global__ void __launch_bounds__(256)
scan_blocksums(const int* __restrict__ counts, int* __restrict__ blockSums) {
    __shared__ int red[256];
    const int t = threadIdx.x;
    const int base = blockIdx.x * SCAN_CHUNK + t * 4;
    int s = 0;
    #pragma unroll
    for (int k = 0; k < 4; ++k) {
        int i = base + k;
        if (i < NN) s += counts[i];
    }
    red[t] = s;
    __syncthreads();
    for (int off = 128; off > 0; off >>= 1) {
        if (t < off) red[t] += red[t + off];
        __syncthreads();
    }
    if (t == 0) blockSums[blockIdx.x] = red[0];
}

// ---------------------------------------------------------------------------
// Scan pass B: exclusive scan of the 245 block sums (single small block)
// ---------------------------------------------------------------------------
__global__ void __launch_bounds__(256)
scan_offsets(const int* __restrict__ blockSums,
             int* __restrict__ blockOffs,
             int* __restrict__ row_ptr) {
    __shared__ int s[256];
    const int t = threadIdx.x;
    int v = (t < SCAN_BLOCKS) ? blockSums[t] : 0;
    s[t] = v;
    __syncthreads();
    for (int off = 1; off < 256; off <<= 1) {
        int u = (t >= off) ? s[t - off] : 0;
        __syncthreads();
        s[t] += u;
        __syncthreads();
    }
    if (t < SCAN_BLOCKS) blockOffs[t] = s[t] - v;   // exclusive
    if (t == 255) row_ptr[NN] = s[255];             // grand total = E
}

// ---------------------------------------------------------------------------
// Scan pass C: intra-block exclusive scan + global offset -> row_ptr
// ---------------------------------------------------------------------------
__global__ void __launch_bounds__(256)
scan_final(const int* __restrict__ counts,
           const int* __restrict__ blockOffs,
           int* __restrict__ row_ptr) {
    __shared__ int s[256];
    const int t = threadIdx.x;
    const int base = blockIdx.x * SCAN_CHUNK + t * 4;
    int c0 = 0, c1 = 0, c2 = 0, c3 = 0;
    if (base + 0 < NN) c0 = counts[base + 0];
    if (base + 1 < NN) c1 = counts[base + 1];
    if (base + 2 < NN) c2 = counts[base + 2];
    if (base + 3 < NN) c3 = counts[base + 3];
    int tsum = c0 + c1 + c2 + c3;
    s[t] = tsum;
    __syncthreads();
    for (int off = 1; off < 256; off <<= 1) {
        int u = (t >= off) ? s[t - off] : 0;
        __syncthreads();
        s[t] += u;
        __syncthreads();
    }
    int run = blockOffs[blockIdx.x] + s[t] - tsum;   // exclusive prefix
    int p0 = run;
    int p1 = p0 + c0;
    int p2 = p1 + c1;
    int p3 = p2 + c2;
    if (base + 0 < NN) row_ptr[base + 0] = p0;
    if (base + 1 < NN) row_ptr[base + 1] = p1;
    if (base + 2 < NN) row_ptr[base + 2] = p2;
    if (base + 3 < NN) row_ptr[base + 3] = p3;
}

// ---------------------------------------------------------------------------
// Bucket cursors for phase A: staging region base = CSR base of the bucket
// ---------------------------------------------------------------------------
__global__ void __launch_bounds__(256)
init_bucket_cursors(const int* __restrict__ row_ptr, int* __restrict__ cursorA) {
    int b = blockIdx.x * blockDim.x + threadIdx.x;
    if (b < NB_BUCKETS) cursorA[b] = row_ptr[b << BSHIFT];
}

// ---------------------------------------------------------------------------
// Phase A: LDS-aggregated bucket append.
// Round-6 structure: cursor reservation is ONE parallel atomic per bucket
// (thread t -> bucket t), then copy-out runs with 16-lane subgroups and no
// atomics/shfl in the loop (kills the round-5 serial atomic chain).
// Staged element: { (row_in_bucket << 18) | col, bits(val) }.
// ---------------------------------------------------------------------------
__global__ void __launch_bounds__(256)
bucket_phaseA(const int*   __restrict__ rows,
              const int*   __restrict__ cols,
              const float* __restrict__ vals,
              int*         __restrict__ cursorA,
              int2*        __restrict__ stage) {
    __shared__ int  cnt[256];
    __shared__ int  off[256];
    __shared__ int  cur[256];
    __shared__ int  gbase[256];
    __shared__ int2 stg[CHUNK_EDGES];    // 32 KB
    const int t = threadIdx.x;
    cnt[t] = 0;
    __syncthreads();

    const int base = blockIdx.x * CHUNK_EDGES;
    int re[CHUNK_EDGES / 256];           // cache rows -> no second global read
    #pragma unroll
    for (int k = 0; k < CHUNK_EDGES / 256; ++k) {
        int e = base + t + k * 256;
        re[k] = (e < E_EDGES) ? rows[e] : -1;
        if (re[k] >= 0) atomicAdd(&cnt[re[k] >> BSHIFT], 1);
    }
    __syncthreads();

    // exclusive scan of cnt -> off (Hillis-Steele over 256)
    int v = cnt[t];
    off[t] = v;
    __syncthreads();
    for (int o = 1; o < 256; o <<= 1) {
        int u = (t >= o) ? off[t - o] : 0;
        __syncthreads();
        off[t] += u;
        __syncthreads();
    }
    int excl = off[t] - v;
    __syncthreads();
    off[t] = excl;
    cur[t] = excl;
    // parallel cursor reservation: one independent atomic per bucket
    if (t < NB_BUCKETS && v > 0) gbase[t] = atomicAdd(&cursorA[t], v);
    __syncthreads();

    // place into LDS staging
    #pragma unroll
    for (int k = 0; k < CHUNK_EDGES / 256; ++k) {
        int r = re[k];
        if (r >= 0) {
            int e = base + t + k * 256;
            int b = r >> BSHIFT;
            int slot = atomicAdd(&cur[b], 1);
            stg[slot] = make_int2(((r & ((1 << BSHIFT) - 1)) << 18) | cols[e],
                                  __float_as_int(vals[e]));
        }
    }
    __syncthreads();

    // copy runs out: 16-lane subgroups (mean run length ~17), no atomics here
    const int sg = t >> 4;    // 0..15
    const int sl = t & 15;
    for (int b = sg; b < NB_BUCKETS; b += 16) {
        int n = cnt[b];
        if (n == 0) continue;
        int gb = gbase[b];
        int lb = off[b];
        for (int i = sl; i < n; i += 16)
            stage[gb + i] = stg[lb + i];
    }
}

// ---------------------------------------------------------------------------
// Phase B: exact CSR placement, ONE block per bucket (single-XCD write region
// of 128 KB -> full cache lines). LDS cursors per row.
// ---------------------------------------------------------------------------
__global__ void __launch_bounds__(256)
bucket_phaseB(const int*  __restrict__ row_ptr,
              const int2* __restrict__ stage,
              int2*       __restrict__ pairs) {
    __shared__ int curs[1 << BSHIFT];    // 1024 row cursors
    const int b = blockIdx.x;
    const int rowBase = b << BSHIFT;
    const int nRows = (NN - rowBase < (1 << BSHIFT)) ? (NN - rowBase) : (1 << BSHIFT);
    const int t = threadIdx.x;
    for (int i = t; i < nRows; i += 256) curs[i] = row_ptr[rowBase + i];
    __syncthreads();
    const int s = row_ptr[rowBase];
    const int e = row_ptr[(rowBase + (1 << BSHIFT) < NN) ? rowBase + (1 << BSHIFT) : NN];
    for (int i = s + t; i < e; i += 256) {
        int2 p = stage[i];
        int rib = p.x >> 18;
        int col = p.x & 0x3FFFF;
        int slot = atomicAdd(&curs[rib], 1);
        pairs[slot] = make_int2(col, p.y);
    }
}

// ---------------------------------------------------------------------------
// Pull-mode SpMM: one wave per destination row, lane = dim.
// ---------------------------------------------------------------------------
template <bool FIRST>
__global__ void __launch_bounds__(256)
spmm_pull(const int*  __restrict__ row_ptr,
          const int2* __restrict__ pairs,
          const float* __restrict__ ut,
          const float* __restrict__ gt,
          const float* __restrict__ x,
          float*       __restrict__ y) {
    int row  = blockIdx.x * 4 + (threadIdx.x >> 6);   // 4 waves / block
    int lane = threadIdx.x & 63;
    if (row >= NN) return;
    int start = row_ptr[row];
    int end   = row_ptr[row + 1];

    auto loadx = [&](int c) -> float {
        if (FIRST) {
            return (c < NUM_USER) ? ut[(size_t)c * D + lane]
                                  : gt[(size_t)(c - NUM_USER) * D + lane];
        } else {
            return x[(size_t)c * D + lane];
        }
    };

    float acc = 0.f;
    int e = start;
    for (; e + 4 <= end; e += 4) {
        int2 p0 = pairs[e + 0];
        int2 p1 = pairs[e + 1];
        int2 p2 = pairs[e + 2];
        int2 p3 = pairs[e + 3];
        float x0 = loadx(p0.x);
        float x1 = loadx(p1.x);
        float x2 = loadx(p2.x);
        float x3 = loadx(p3.x);
        acc += __int_as_float(p0.y) * x0;
        acc += __int_as_float(p1.y) * x1;
        acc += __int_as_float(p2.y) * x2;
        acc += __int_as_float(p3.y) * x3;
    }
    for (; e < end; ++e) {
        int2 p = pairs[e];
        acc += __int_as_float(p.y) * loadx(p.x);
    }
    y[(size_t)row * D + lane] = acc;
}

// ---------------------------------------------------------------------------
// Output init: raw table gathers (outputs 3..5) and the level-0 contribution
// ---------------------------------------------------------------------------
__global__ void gather_init(const float* __restrict__ ut,
                            const float* __restrict__ gt,
                            const int*   __restrict__ ui,
                            const int*   __restrict__ pg,
                            const int*   __restrict__ ng,
                            float*       __restrict__ out) {
    int i = blockIdx.x * blockDim.x + threadIdx.x;    // B*D threads
    if (i >= B * D) return;
    int b = i >> 6, d = i & 63;
    float u = ut[(size_t)ui[b] * D + d];
    float p = gt[(size_t)pg[b] * D + d];
    float n = gt[(size_t)ng[b] * D + d];
    const int S = B * D;
    out[0 * S + i] = 0.25f * u;
    out[1 * S + i] = 0.25f * p;
    out[2 * S + i] = 0.25f * n;
    out[3 * S + i] = u;
    out[4 * S + i] = p;
    out[5 * S + i] = n;
}

// ---------------------------------------------------------------------------
// Per-level accumulation of 0.25 * emb_l at the gathered rows
// ---------------------------------------------------------------------------
__global__ void gather_acc(const float* __restrict__ emb,
                           const int*   __restrict__ ui,
                           const int*   __restrict__ pg,
                           const int*   __restrict__ ng,
                           float*       __restrict__ out) {
    int i = blockIdx.x * blockDim.x + threadIdx.x;    // B*D threads
    if (i >= B * D) return;
    int b = i >> 6, d = i & 63;
    const int S = B * D;
    out[0 * S + i] += 0.25f * emb[(size_t)ui[b] * D + d];
    out[1 * S + i] += 0.25f * emb[((size_t)NUM_USER + pg[b]) * D + d];
    out[2 * S + i] += 0.25f * emb[((size_t)NUM_USER + ng[b]) * D + d];
}

// ---------------------------------------------------------------------------
extern "C" void kernel_launch(void* const* d_in, const int* in_sizes, int n_in,
                              void* d_out, int out_size, void* d_ws, size_t ws_size,
                              hipStream_t stream) {
    const float* ut   = (const float*)d_in[0];
    const float* gt   = (const float*)d_in[1];
    const float* vals = (const float*)d_in[2];
    const int*   rows = (const int*)d_in[3];
    const int*   cols = (const int*)d_in[4];
    const int*   ui   = (const int*)d_in[5];
    const int*   pg   = (const int*)d_in[6];
    const int*   ng   = (const int*)d_in[7];
    float* out = (float*)d_out;

    // --- workspace layout ---
    char* ws = (char*)d_ws;
    float* emb_a   = (float*)ws;   ws += (size_t)NN * D * sizeof(float);   // 64 MB
    float* emb_b   = (float*)ws;   ws += (size_t)NN * D * sizeof(float);   // 64 MB
    int2*  pairs   = (int2*)ws;    ws += (size_t)E_EDGES * sizeof(int2);   // 32 MB
    int*   row_ptr = (int*)ws;     ws += (size_t)(NN + 1) * sizeof(int);
    int*   counts  = (int*)ws;     ws += (size_t)NN * sizeof(int);
    int*   blockSums = (int*)ws;   ws += (size_t)SCAN_BLOCKS * sizeof(int);
    int*   blockOffs = (int*)ws;   ws += (size_t)SCAN_BLOCKS * sizeof(int);
    int*   cursorA   = (int*)ws;   ws += (size_t)NB_BUCKETS * sizeof(int);
    // phase-A staging aliases emb_b (dead until SpMM level 2)
    int2* stage = (int2*)emb_b;                                            // 32 MB

    // --- CSR build (once per call; reused for all 3 levels) ---
    hipMemsetAsync(counts, 0, (size_t)NN * sizeof(int), stream);
    hist_kernel<<<(E_EDGES + 255) / 256, 256, 0, stream>>>(rows, counts);
    scan_blocksums<<<SCAN_BLOCKS, 256, 0, stream>>>(counts, blockSums);
    scan_offsets<<<1, 256, 0, stream>>>(blockSums, blockOffs, row_ptr);
    scan_final<<<SCAN_BLOCKS, 256, 0, stream>>>(counts, blockOffs, row_ptr);
    init_bucket_cursors<<<1, 256, 0, stream>>>(row_ptr, cursorA);
    bucket_phaseA<<<(E_EDGES + CHUNK_EDGES - 1) / CHUNK_EDGES, 256, 0, stream>>>(
        rows, cols, vals, cursorA, stage);
    bucket_phaseB<<<NB_BUCKETS, 256, 0, stream>>>(row_ptr, stage, pairs);

    // --- outputs 3..5 + level-0 contribution ---
    gather_init<<<(B * D + 255) / 256, 256, 0, stream>>>(ut, gt, ui, pg, ng, out);

    // --- 3 propagation levels, pull mode ---
    const int spmmBlocks = (NN + 3) / 4;   // 4 rows (waves) per 256-thread block
    spmm_pull<true><<<spmmBlocks, 256, 0, stream>>>(row_ptr, pairs, ut, gt, nullptr, emb_a);
    gather_acc<<<(B * D + 255) / 256, 256, 0, stream>>>(emb_a, ui, pg, ng, out);

    spmm_pull<false><<<spmmBlocks, 256, 0, stream>>>(row_ptr, pairs, ut, gt, emb_a, emb_b);
    gather_acc<<<(B * D + 255) / 256, 256, 0, stream>>>(emb_b, ui, pg, ng, out);

    spmm_pull<false><<<spmmBlocks, 256, 0, stream>>>(row_ptr, pairs, ut, gt, emb_b, emb_a);
    gather_acc<<<(B * D + 255) / 256, 256, 0, stream>>>(emb_a, ui, pg, ng, out);
}

// Round 7
// 767.022 us; speedup vs baseline: 1.7485x; 1.1914x over previous
//
#include <hip/hip_runtime.h>

#define NUM_USER  200000
#define NUM_GROUP 50000
#define NN        (NUM_USER + NUM_GROUP)   // 250000
#define E_EDGES   4000000
#define D         64
#define B         8192

#define SCAN_CHUNK   1024                                   // counts per block
#define SCAN_BLOCKS  ((NN + SCAN_CHUNK - 1) / SCAN_CHUNK)   // 245

#define BSHIFT       10                                     // 1024 rows / bucket
#define NB_BUCKETS   ((NN + (1 << BSHIFT) - 1) >> BSHIFT)   // 245
#define CHUNK_EDGES  4096                                   // edges per phase-A block

// ---------------------------------------------------------------------------
// CSR build step 1: histogram of destination rows
// ---------------------------------------------------------------------------
__global__ void __launch_bounds__(256)
hist_kernel(const int* __restrict__ rows, int* __restrict__ counts) {
    int e = blockIdx.x * blockDim.x + threadIdx.x;
    if (e >= E_EDGES) return;
    atomicAdd(&counts[rows[e]], 1);
}

// ---------------------------------------------------------------------------
// Scan pass A: per-block sums of 1024 counts each
// ---------------------------------------------------------------------------
__global__ void __launch_bounds__(256)
scan_blocksums(const int* __restrict__ counts, int* __restrict__ blockSums) {
    __shared__ int red[256];
    const int t = threadIdx.x;
    const int base = blockIdx.x * SCAN_CHUNK + t * 4;
    int s = 0;
    #pragma unroll
    for (int k = 0; k < 4; ++k) {
        int i = base + k;
        if (i < NN) s += counts[i];
    }
    red[t] = s;
    __syncthreads();
    for (int off = 128; off > 0; off >>= 1) {
        if (t < off) red[t] += red[t + off];
        __syncthreads();
    }
    if (t == 0) blockSums[blockIdx.x] = red[0];
}

// ---------------------------------------------------------------------------
// Scan pass B: exclusive scan of the 245 block sums (single small block)
// ---------------------------------------------------------------------------
__global__ void __launch_bounds__(256)
scan_offsets(const int* __restrict__ blockSums,
             int* __restrict__ blockOffs,
             int* __restrict__ row_ptr) {
    __shared__ int s[256];
    const int t = threadIdx.x;
    int v = (t < SCAN_BLOCKS) ? blockSums[t] : 0;
    s[t] = v;
    __syncthreads();
    for (int off = 1; off < 256; off <<= 1) {
        int u = (t >= off) ? s[t - off] : 0;
        __syncthreads();
        s[t] += u;
        __syncthreads();
    }
    if (t < SCAN_BLOCKS) blockOffs[t] = s[t] - v;   // exclusive
    if (t == 255) row_ptr[NN] = s[255];             // grand total = E
}

// ---------------------------------------------------------------------------
// Scan pass C: intra-block exclusive scan + global offset -> row_ptr
// ---------------------------------------------------------------------------
__global__ void __launch_bounds__(256)
scan_final(const int* __restrict__ counts,
           const int* __restrict__ blockOffs,
           int* __restrict__ row_ptr) {
    __shared__ int s[256];
    const int t = threadIdx.x;
    const int base = blockIdx.x * SCAN_CHUNK + t * 4;
    int c0 = 0, c1 = 0, c2 = 0, c3 = 0;
    if (base + 0 < NN) c0 = counts[base + 0];
    if (base + 1 < NN) c1 = counts[base + 1];
    if (base + 2 < NN) c2 = counts[base + 2];
    if (base + 3 < NN) c3 = counts[base + 3];
    int tsum = c0 + c1 + c2 + c3;
    s[t] = tsum;
    __syncthreads();
    for (int off = 1; off < 256; off <<= 1) {
        int u = (t >= off) ? s[t - off] : 0;
        __syncthreads();
        s[t] += u;
        __syncthreads();
    }
    int run = blockOffs[blockIdx.x] + s[t] - tsum;   // exclusive prefix
    int p0 = run;
    int p1 = p0 + c0;
    int p2 = p1 + c1;
    int p3 = p2 + c2;
    if (base + 0 < NN) row_ptr[base + 0] = p0;
    if (base + 1 < NN) row_ptr[base + 1] = p1;
    if (base + 2 < NN) row_ptr[base + 2] = p2;
    if (base + 3 < NN) row_ptr[base + 3] = p3;
}

// ---------------------------------------------------------------------------
// Bucket cursors for phase A: staging region base = CSR base of the bucket
// ---------------------------------------------------------------------------
__global__ void __launch_bounds__(256)
init_bucket_cursors(const int* __restrict__ row_ptr, int* __restrict__ cursorA) {
    int b = blockIdx.x * blockDim.x + threadIdx.x;
    if (b < NB_BUCKETS) cursorA[b] = row_ptr[b << BSHIFT];
}

// ---------------------------------------------------------------------------
// Phase A: LDS-aggregated bucket append (round-6 structure: parallel cursor
// reservation, 16-lane subgroup copy-out).
// Staged element: { (row_in_bucket << 18) | col, bits(val) }.
// ---------------------------------------------------------------------------
__global__ void __launch_bounds__(256)
bucket_phaseA(const int*   __restrict__ rows,
              const int*   __restrict__ cols,
              const float* __restrict__ vals,
              int*         __restrict__ cursorA,
              int2*        __restrict__ stage) {
    __shared__ int  cnt[256];
    __shared__ int  off[256];
    __shared__ int  cur[256];
    __shared__ int  gbase[256];
    __shared__ int2 stg[CHUNK_EDGES];    // 32 KB
    const int t = threadIdx.x;
    cnt[t] = 0;
    __syncthreads();

    const int base = blockIdx.x * CHUNK_EDGES;
    int re[CHUNK_EDGES / 256];           // cache rows -> no second global read
    #pragma unroll
    for (int k = 0; k < CHUNK_EDGES / 256; ++k) {
        int e = base + t + k * 256;
        re[k] = (e < E_EDGES) ? rows[e] : -1;
        if (re[k] >= 0) atomicAdd(&cnt[re[k] >> BSHIFT], 1);
    }
    __syncthreads();

    // exclusive scan of cnt -> off (Hillis-Steele over 256)
    int v = cnt[t];
    off[t] = v;
    __syncthreads();
    for (int o = 1; o < 256; o <<= 1) {
        int u = (t >= o) ? off[t - o] : 0;
        __syncthreads();
        off[t] += u;
        __syncthreads();
    }
    int excl = off[t] - v;
    __syncthreads();
    off[t] = excl;
    cur[t] = excl;
    // parallel cursor reservation: one independent atomic per bucket
    if (t < NB_BUCKETS && v > 0) gbase[t] = atomicAdd(&cursorA[t], v);
    __syncthreads();

    // place into LDS staging
    #pragma unroll
    for (int k = 0; k < CHUNK_EDGES / 256; ++k) {
        int r = re[k];
        if (r >= 0) {
            int e = base + t + k * 256;
            int b = r >> BSHIFT;
            int slot = atomicAdd(&cur[b], 1);
            stg[slot] = make_int2(((r & ((1 << BSHIFT) - 1)) << 18) | cols[e],
                                  __float_as_int(vals[e]));
        }
    }
    __syncthreads();

    // copy runs out: 16-lane subgroups (mean run length ~17), no atomics here
    const int sg = t >> 4;    // 0..15
    const int sl = t & 15;
    for (int b = sg; b < NB_BUCKETS; b += 16) {
        int n = cnt[b];
        if (n == 0) continue;
        int gb = gbase[b];
        int lb = off[b];
        for (int i = sl; i < n; i += 16)
            stage[gb + i] = stg[lb + i];
    }
}

// ---------------------------------------------------------------------------
// Phase B: exact CSR placement, ONE block per bucket. LDS cursors per row.
// ---------------------------------------------------------------------------
__global__ void __launch_bounds__(256)
bucket_phaseB(const int*  __restrict__ row_ptr,
              const int2* __restrict__ stage,
              int2*       __restrict__ pairs) {
    __shared__ int curs[1 << BSHIFT];    // 1024 row cursors
    const int b = blockIdx.x;
    const int rowBase = b << BSHIFT;
    const int nRows = (NN - rowBase < (1 << BSHIFT)) ? (NN - rowBase) : (1 << BSHIFT);
    const int t = threadIdx.x;
    for (int i = t; i < nRows; i += 256) curs[i] = row_ptr[rowBase + i];
    __syncthreads();
    const int s = row_ptr[rowBase];
    const int e = row_ptr[(rowBase + (1 << BSHIFT) < NN) ? rowBase + (1 << BSHIFT) : NN];
    for (int i = s + t; i < e; i += 256) {
        int2 p = stage[i];
        int rib = p.x >> 18;
        int col = p.x & 0x3FFFF;
        int slot = atomicAdd(&curs[rib], 1);
        pairs[slot] = make_int2(col, p.y);
    }
}

// ---------------------------------------------------------------------------
// Pull-mode SpMM: one wave per destination row, lane = dim.
// ---------------------------------------------------------------------------
template <bool FIRST>
__global__ void __launch_bounds__(256)
spmm_pull(const int*  __restrict__ row_ptr,
          const int2* __restrict__ pairs,
          const float* __restrict__ ut,
          const float* __restrict__ gt,
          const float* __restrict__ x,
          float*       __restrict__ y) {
    int row  = blockIdx.x * 4 + (threadIdx.x >> 6);   // 4 waves / block
    int lane = threadIdx.x & 63;
    if (row >= NN) return;
    int start = row_ptr[row];
    int end   = row_ptr[row + 1];

    auto loadx = [&](int c) -> float {
        if (FIRST) {
            return (c < NUM_USER) ? ut[(size_t)c * D + lane]
                                  : gt[(size_t)(c - NUM_USER) * D + lane];
        } else {
            return x[(size_t)c * D + lane];
        }
    };

    float acc = 0.f;
    int e = start;
    for (; e + 4 <= end; e += 4) {
        int2 p0 = pairs[e + 0];
        int2 p1 = pairs[e + 1];
        int2 p2 = pairs[e + 2];
        int2 p3 = pairs[e + 3];
        float x0 = loadx(p0.x);
        float x1 = loadx(p1.x);
        float x2 = loadx(p2.x);
        float x3 = loadx(p3.x);
        acc += __int_as_float(p0.y) * x0;
        acc += __int_as_float(p1.y) * x1;
        acc += __int_as_float(p2.y) * x2;
        acc += __int_as_float(p3.y) * x3;
    }
    for (; e < end; ++e) {
        int2 p = pairs[e];
        acc += __int_as_float(p.y) * loadx(p.x);
    }
    y[(size_t)row * D + lane] = acc;
}

// ---------------------------------------------------------------------------
// Final level, output-sparse: one wave per OUTPUT SLOT (3*B slots). Pulls the
// slot's row from the CSR over emb2 and adds 0.25 * sum into d_out directly.
// emb3 is never materialized (only 24576 of 250000 rows are ever read).
// ---------------------------------------------------------------------------
__global__ void __launch_bounds__(256)
final_pull(const int*  __restrict__ row_ptr,
           const int2* __restrict__ pairs,
           const float* __restrict__ x,      // emb2
           const int*  __restrict__ ui,
           const int*  __restrict__ pg,
           const int*  __restrict__ ng,
           float*      __restrict__ out) {
    int slot = blockIdx.x * 4 + (threadIdx.x >> 6);   // 0 .. 3*B-1
    int lane = threadIdx.x & 63;
    if (slot >= 3 * B) return;
    int region = slot / B;                 // 0=user, 1=pos, 2=neg
    int b      = slot - region * B;
    int row;
    if (region == 0)      row = ui[b];
    else if (region == 1) row = NUM_USER + pg[b];
    else                  row = NUM_USER + ng[b];

    int start = row_ptr[row];
    int end   = row_ptr[row + 1];
    float acc = 0.f;
    int e = start;
    for (; e + 4 <= end; e += 4) {
        int2 p0 = pairs[e + 0];
        int2 p1 = pairs[e + 1];
        int2 p2 = pairs[e + 2];
        int2 p3 = pairs[e + 3];
        float x0 = x[(size_t)p0.x * D + lane];
        float x1 = x[(size_t)p1.x * D + lane];
        float x2 = x[(size_t)p2.x * D + lane];
        float x3 = x[(size_t)p3.x * D + lane];
        acc += __int_as_float(p0.y) * x0;
        acc += __int_as_float(p1.y) * x1;
        acc += __int_as_float(p2.y) * x2;
        acc += __int_as_float(p3.y) * x3;
    }
    for (; e < end; ++e) {
        int2 p = pairs[e];
        acc += __int_as_float(p.y) * x[(size_t)p.x * D + lane];
    }
    out[(size_t)region * B * D + (size_t)b * D + lane] += 0.25f * acc;
}

// ---------------------------------------------------------------------------
// Output init: raw table gathers (outputs 3..5) and the level-0 contribution
// ---------------------------------------------------------------------------
__global__ void gather_init(const float* __restrict__ ut,
                            const float* __restrict__ gt,
                            const int*   __restrict__ ui,
                            const int*   __restrict__ pg,
                            const int*   __restrict__ ng,
                            float*       __restrict__ out) {
    int i = blockIdx.x * blockDim.x + threadIdx.x;    // B*D threads
    if (i >= B * D) return;
    int b = i >> 6, d = i & 63;
    float u = ut[(size_t)ui[b] * D + d];
    float p = gt[(size_t)pg[b] * D + d];
    float n = gt[(size_t)ng[b] * D + d];
    const int S = B * D;
    out[0 * S + i] = 0.25f * u;
    out[1 * S + i] = 0.25f * p;
    out[2 * S + i] = 0.25f * n;
    out[3 * S + i] = u;
    out[4 * S + i] = p;
    out[5 * S + i] = n;
}

// ---------------------------------------------------------------------------
// Per-level accumulation of 0.25 * emb_l at the gathered rows
// ---------------------------------------------------------------------------
__global__ void gather_acc(const float* __restrict__ emb,
                           const int*   __restrict__ ui,
                           const int*   __restrict__ pg,
                           const int*   __restrict__ ng,
                           float*       __restrict__ out) {
    int i = blockIdx.x * blockDim.x + threadIdx.x;    // B*D threads
    if (i >= B * D) return;
    int b = i >> 6, d = i & 63;
    const int S = B * D;
    out[0 * S + i] += 0.25f * emb[(size_t)ui[b] * D + d];
    out[1 * S + i] += 0.25f * emb[((size_t)NUM_USER + pg[b]) * D + d];
    out[2 * S + i] += 0.25f * emb[((size_t)NUM_USER + ng[b]) * D + d];
}

// ---------------------------------------------------------------------------
extern "C" void kernel_launch(void* const* d_in, const int* in_sizes, int n_in,
                              void* d_out, int out_size, void* d_ws, size_t ws_size,
                              hipStream_t stream) {
    const float* ut   = (const float*)d_in[0];
    const float* gt   = (const float*)d_in[1];
    const float* vals = (const float*)d_in[2];
    const int*   rows = (const int*)d_in[3];
    const int*   cols = (const int*)d_in[4];
    const int*   ui   = (const int*)d_in[5];
    const int*   pg   = (const int*)d_in[6];
    const int*   ng   = (const int*)d_in[7];
    float* out = (float*)d_out;

    // --- workspace layout ---
    char* ws = (char*)d_ws;
    float* emb_a   = (float*)ws;   ws += (size_t)NN * D * sizeof(float);   // 64 MB
    float* emb_b   = (float*)ws;   ws += (size_t)NN * D * sizeof(float);   // 64 MB
    int2*  pairs   = (int2*)ws;    ws += (size_t)E_EDGES * sizeof(int2);   // 32 MB
    int*   row_ptr = (int*)ws;     ws += (size_t)(NN + 1) * sizeof(int);
    int*   counts  = (int*)ws;     ws += (size_t)NN * sizeof(int);
    int*   blockSums = (int*)ws;   ws += (size_t)SCAN_BLOCKS * sizeof(int);
    int*   blockOffs = (int*)ws;   ws += (size_t)SCAN_BLOCKS * sizeof(int);
    int*   cursorA   = (int*)ws;   ws += (size_t)NB_BUCKETS * sizeof(int);
    // phase-A staging aliases emb_b (dead until SpMM level 2)
    int2* stage = (int2*)emb_b;                                            // 32 MB

    // --- CSR build (once per call; reused for all 3 levels) ---
    hipMemsetAsync(counts, 0, (size_t)NN * sizeof(int), stream);
    hist_kernel<<<(E_EDGES + 255) / 256, 256, 0, stream>>>(rows, counts);
    scan_blocksums<<<SCAN_BLOCKS, 256, 0, stream>>>(counts, blockSums);
    scan_offsets<<<1, 256, 0, stream>>>(blockSums, blockOffs, row_ptr);
    scan_final<<<SCAN_BLOCKS, 256, 0, stream>>>(counts, blockOffs, row_ptr);
    init_bucket_cursors<<<1, 256, 0, stream>>>(row_ptr, cursorA);
    bucket_phaseA<<<(E_EDGES + CHUNK_EDGES - 1) / CHUNK_EDGES, 256, 0, stream>>>(
        rows, cols, vals, cursorA, stage);
    bucket_phaseB<<<NB_BUCKETS, 256, 0, stream>>>(row_ptr, stage, pairs);

    // --- outputs 3..5 + level-0 contribution ---
    gather_init<<<(B * D + 255) / 256, 256, 0, stream>>>(ut, gt, ui, pg, ng, out);

    // --- propagation: 2 full levels + output-sparse final level ---
    const int spmmBlocks = (NN + 3) / 4;   // 4 rows (waves) per 256-thread block
    spmm_pull<true><<<spmmBlocks, 256, 0, stream>>>(row_ptr, pairs, ut, gt, nullptr, emb_a);
    gather_acc<<<(B * D + 255) / 256, 256, 0, stream>>>(emb_a, ui, pg, ng, out);

    spmm_pull<false><<<spmmBlocks, 256, 0, stream>>>(row_ptr, pairs, ut, gt, emb_a, emb_b);
    gather_acc<<<(B * D + 255) / 256, 256, 0, stream>>>(emb_b, ui, pg, ng, out);

    // level 3: only the 24576 output rows, fused into the output accumulation
    final_pull<<<(3 * B + 3) / 4, 256, 0, stream>>>(row_ptr, pairs, emb_b, ui, pg, ng, out);
}

// Round 8
// 735.243 us; speedup vs baseline: 1.8240x; 1.0432x over previous
//
#include <hip/hip_runtime.h>

#define NUM_USER  200000
#define NUM_GROUP 50000
#define NN        (NUM_USER + NUM_GROUP)   // 250000
#define E_EDGES   4000000
#define D         64
#define B         8192

#define SCAN_CHUNK   1024                                   // counts per block
#define SCAN_BLOCKS  ((NN + SCAN_CHUNK - 1) / SCAN_CHUNK)   // 245

#define BSHIFT       10                                     // 1024 rows / bucket
#define NB_BUCKETS   ((NN + (1 << BSHIFT) - 1) >> BSHIFT)   // 245
#define CHUNK_EDGES  4096                                   // edges per phase-A block

// --- bf16 helpers (RNE; values are normal floats, no NaN path needed) ------
__device__ __forceinline__ float bf2f(unsigned short u) {
    return __uint_as_float(((unsigned int)u) << 16);
}
__device__ __forceinline__ unsigned short f2bf(float f) {
    unsigned int x = __float_as_uint(f);
    return (unsigned short)((x + 0x7FFFu + ((x >> 16) & 1u)) >> 16);
}

// ---------------------------------------------------------------------------
// Convert concat(user_table, group_table) fp32 -> bf16 emb0 (vectorized x4)
// ---------------------------------------------------------------------------
__global__ void __launch_bounds__(256)
convert_tables(const float* __restrict__ ut,
               const float* __restrict__ gt,
               unsigned short* __restrict__ embT) {
    const long long total4 = (long long)NN * D / 4;
    const long long user4  = (long long)NUM_USER * D / 4;
    long long i = (long long)blockIdx.x * blockDim.x + threadIdx.x;
    if (i >= total4) return;
    float4 v = (i < user4) ? ((const float4*)ut)[i] : ((const float4*)gt)[i - user4];
    ushort4 o;
    o.x = f2bf(v.x); o.y = f2bf(v.y); o.z = f2bf(v.z); o.w = f2bf(v.w);
    ((ushort4*)embT)[i] = o;
}

// ---------------------------------------------------------------------------
// CSR build step 1: histogram of destination rows
// ---------------------------------------------------------------------------
__global__ void __launch_bounds__(256)
hist_kernel(const int* __restrict__ rows, int* __restrict__ counts) {
    int e = blockIdx.x * blockDim.x + threadIdx.x;
    if (e >= E_EDGES) return;
    atomicAdd(&counts[rows[e]], 1);
}

// ---------------------------------------------------------------------------
// Scan pass A: per-block sums of 1024 counts each
// ---------------------------------------------------------------------------
__global__ void __launch_bounds__(256)
scan_blocksums(const int* __restrict__ counts, int* __restrict__ blockSums) {
    __shared__ int red[256];
    const int t = threadIdx.x;
    const int base = blockIdx.x * SCAN_CHUNK + t * 4;
    int s = 0;
    #pragma unroll
    for (int k = 0; k < 4; ++k) {
        int i = base + k;
        if (i < NN) s += counts[i];
    }
    red[t] = s;
    __syncthreads();
    for (int off = 128; off > 0; off >>= 1) {
        if (t < off) red[t] += red[t + off];
        __syncthreads();
    }
    if (t == 0) blockSums[blockIdx.x] = red[0];
}

// ---------------------------------------------------------------------------
// Scan pass B: exclusive scan of the 245 block sums (single small block)
// ---------------------------------------------------------------------------
__global__ void __launch_bounds__(256)
scan_offsets(const int* __restrict__ blockSums,
             int* __restrict__ blockOffs,
             int* __restrict__ row_ptr) {
    __shared__ int s[256];
    const int t = threadIdx.x;
    int v = (t < SCAN_BLOCKS) ? blockSums[t] : 0;
    s[t] = v;
    __syncthreads();
    for (int off = 1; off < 256; off <<= 1) {
        int u = (t >= off) ? s[t - off] : 0;
        __syncthreads();
        s[t] += u;
        __syncthreads();
    }
    if (t < SCAN_BLOCKS) blockOffs[t] = s[t] - v;   // exclusive
    if (t == 255) row_ptr[NN] = s[255];             // grand total = E
}

// ---------------------------------------------------------------------------
// Scan pass C: intra-block exclusive scan + global offset -> row_ptr
// ---------------------------------------------------------------------------
__global__ void __launch_bounds__(256)
scan_final(const int* __restrict__ counts,
           const int* __restrict__ blockOffs,
           int* __restrict__ row_ptr) {
    __shared__ int s[256];
    const int t = threadIdx.x;
    const int base = blockIdx.x * SCAN_CHUNK + t * 4;
    int c0 = 0, c1 = 0, c2 = 0, c3 = 0;
    if (base + 0 < NN) c0 = counts[base + 0];
    if (base + 1 < NN) c1 = counts[base + 1];
    if (base + 2 < NN) c2 = counts[base + 2];
    if (base + 3 < NN) c3 = counts[base + 3];
    int tsum = c0 + c1 + c2 + c3;
    s[t] = tsum;
    __syncthreads();
    for (int off = 1; off < 256; off <<= 1) {
        int u = (t >= off) ? s[t - off] : 0;
        __syncthreads();
        s[t] += u;
        __syncthreads();
    }
    int run = blockOffs[blockIdx.x] + s[t] - tsum;   // exclusive prefix
    int p0 = run;
    int p1 = p0 + c0;
    int p2 = p1 + c1;
    int p3 = p2 + c2;
    if (base + 0 < NN) row_ptr[base + 0] = p0;
    if (base + 1 < NN) row_ptr[base + 1] = p1;
    if (base + 2 < NN) row_ptr[base + 2] = p2;
    if (base + 3 < NN) row_ptr[base + 3] = p3;
}

// ---------------------------------------------------------------------------
// Bucket cursors for phase A: staging region base = CSR base of the bucket
// ---------------------------------------------------------------------------
__global__ void __launch_bounds__(256)
init_bucket_cursors(const int* __restrict__ row_ptr, int* __restrict__ cursorA) {
    int b = blockIdx.x * blockDim.x + threadIdx.x;
    if (b < NB_BUCKETS) cursorA[b] = row_ptr[b << BSHIFT];
}

// ---------------------------------------------------------------------------
// Phase A: LDS-aggregated bucket append (parallel cursor reservation,
// 16-lane subgroup copy-out).
// Staged element: { (row_in_bucket << 18) | col, bits(val) }.
// ---------------------------------------------------------------------------
__global__ void __launch_bounds__(256)
bucket_phaseA(const int*   __restrict__ rows,
              const int*   __restrict__ cols,
              const float* __restrict__ vals,
              int*         __restrict__ cursorA,
              int2*        __restrict__ stage) {
    __shared__ int  cnt[256];
    __shared__ int  off[256];
    __shared__ int  cur[256];
    __shared__ int  gbase[256];
    __shared__ int2 stg[CHUNK_EDGES];    // 32 KB
    const int t = threadIdx.x;
    cnt[t] = 0;
    __syncthreads();

    const int base = blockIdx.x * CHUNK_EDGES;
    int re[CHUNK_EDGES / 256];           // cache rows -> no second global read
    #pragma unroll
    for (int k = 0; k < CHUNK_EDGES / 256; ++k) {
        int e = base + t + k * 256;
        re[k] = (e < E_EDGES) ? rows[e] : -1;
        if (re[k] >= 0) atomicAdd(&cnt[re[k] >> BSHIFT], 1);
    }
    __syncthreads();

    // exclusive scan of cnt -> off (Hillis-Steele over 256)
    int v = cnt[t];
    off[t] = v;
    __syncthreads();
    for (int o = 1; o < 256; o <<= 1) {
        int u = (t >= o) ? off[t - o] : 0;
        __syncthreads();
        off[t] += u;
        __syncthreads();
    }
    int excl = off[t] - v;
    __syncthreads();
    off[t] = excl;
    cur[t] = excl;
    // parallel cursor reservation: one independent atomic per bucket
    if (t < NB_BUCKETS && v > 0) gbase[t] = atomicAdd(&cursorA[t], v);
    __syncthreads();

    // place into LDS staging
    #pragma unroll
    for (int k = 0; k < CHUNK_EDGES / 256; ++k) {
        int r = re[k];
        if (r >= 0) {
            int e = base + t + k * 256;
            int b = r >> BSHIFT;
            int slot = atomicAdd(&cur[b], 1);
            stg[slot] = make_int2(((r & ((1 << BSHIFT) - 1)) << 18) | cols[e],
                                  __float_as_int(vals[e]));
        }
    }
    __syncthreads();

    // copy runs out: 16-lane subgroups (mean run length ~17), no atomics here
    const int sg = t >> 4;    // 0..15
    const int sl = t & 15;
    for (int b = sg; b < NB_BUCKETS; b += 16) {
        int n = cnt[b];
        if (n == 0) continue;
        int gb = gbase[b];
        int lb = off[b];
        for (int i = sl; i < n; i += 16)
            stage[gb + i] = stg[lb + i];
    }
}

// ---------------------------------------------------------------------------
// Phase B: exact CSR placement, ONE block per bucket. LDS cursors per row.
// ---------------------------------------------------------------------------
__global__ void __launch_bounds__(256)
bucket_phaseB(const int*  __restrict__ row_ptr,
              const int2* __restrict__ stage,
              int2*       __restrict__ pairs) {
    __shared__ int curs[1 << BSHIFT];    // 1024 row cursors
    const int b = blockIdx.x;
    const int rowBase = b << BSHIFT;
    const int nRows = (NN - rowBase < (1 << BSHIFT)) ? (NN - rowBase) : (1 << BSHIFT);
    const int t = threadIdx.x;
    for (int i = t; i < nRows; i += 256) curs[i] = row_ptr[rowBase + i];
    __syncthreads();
    const int s = row_ptr[rowBase];
    const int e = row_ptr[(rowBase + (1 << BSHIFT) < NN) ? rowBase + (1 << BSHIFT) : NN];
    for (int i = s + t; i < e; i += 256) {
        int2 p = stage[i];
        int rib = p.x >> 18;
        int col = p.x & 0x3FFFF;
        int slot = atomicAdd(&curs[rib], 1);
        pairs[slot] = make_int2(col, p.y);
    }
}

// ---------------------------------------------------------------------------
// Pull-mode SpMM over bf16 embeddings: one wave per destination row,
// lane = dim. fp32 accumulate, bf16 store.
// ---------------------------------------------------------------------------
__global__ void __launch_bounds__(256)
spmm_pull_bf(const int*  __restrict__ row_ptr,
             const int2* __restrict__ pairs,
             const unsigned short* __restrict__ x,
             unsigned short*       __restrict__ y) {
    int row  = blockIdx.x * 4 + (threadIdx.x >> 6);   // 4 waves / block
    int lane = threadIdx.x & 63;
    if (row >= NN) return;
    int start = row_ptr[row];
    int end   = row_ptr[row + 1];

    float acc = 0.f;
    int e = start;
    for (; e + 4 <= end; e += 4) {
        int2 p0 = pairs[e + 0];
        int2 p1 = pairs[e + 1];
        int2 p2 = pairs[e + 2];
        int2 p3 = pairs[e + 3];
        float x0 = bf2f(x[(size_t)p0.x * D + lane]);
        float x1 = bf2f(x[(size_t)p1.x * D + lane]);
        float x2 = bf2f(x[(size_t)p2.x * D + lane]);
        float x3 = bf2f(x[(size_t)p3.x * D + lane]);
        acc += __int_as_float(p0.y) * x0;
        acc += __int_as_float(p1.y) * x1;
        acc += __int_as_float(p2.y) * x2;
        acc += __int_as_float(p3.y) * x3;
    }
    for (; e < end; ++e) {
        int2 p = pairs[e];
        acc += __int_as_float(p.y) * bf2f(x[(size_t)p.x * D + lane]);
    }
    y[(size_t)row * D + lane] = f2bf(acc);
}

// ---------------------------------------------------------------------------
// Final level, output-sparse: one wave per OUTPUT SLOT (3*B slots). Pulls the
// slot's row from the CSR over emb2 (bf16) and adds 0.25*sum into d_out.
// ---------------------------------------------------------------------------
__global__ void __launch_bounds__(256)
final_pull(const int*  __restrict__ row_ptr,
           const int2* __restrict__ pairs,
           const unsigned short* __restrict__ x,      // emb2 bf16
           const int*  __restrict__ ui,
           const int*  __restrict__ pg,
           const int*  __restrict__ ng,
           float*      __restrict__ out) {
    int slot = blockIdx.x * 4 + (threadIdx.x >> 6);   // 0 .. 3*B-1
    int lane = threadIdx.x & 63;
    if (slot >= 3 * B) return;
    int region = slot / B;                 // 0=user, 1=pos, 2=neg
    int b      = slot - region * B;
    int row;
    if (region == 0)      row = ui[b];
    else if (region == 1) row = NUM_USER + pg[b];
    else                  row = NUM_USER + ng[b];

    int start = row_ptr[row];
    int end   = row_ptr[row + 1];
    float acc = 0.f;
    int e = start;
    for (; e + 4 <= end; e += 4) {
        int2 p0 = pairs[e + 0];
        int2 p1 = pairs[e + 1];
        int2 p2 = pairs[e + 2];
        int2 p3 = pairs[e + 3];
        float x0 = bf2f(x[(size_t)p0.x * D + lane]);
        float x1 = bf2f(x[(size_t)p1.x * D + lane]);
        float x2 = bf2f(x[(size_t)p2.x * D + lane]);
        float x3 = bf2f(x[(size_t)p3.x * D + lane]);
        acc += __int_as_float(p0.y) * x0;
        acc += __int_as_float(p1.y) * x1;
        acc += __int_as_float(p2.y) * x2;
        acc += __int_as_float(p3.y) * x3;
    }
    for (; e < end; ++e) {
        int2 p = pairs[e];
        acc += __int_as_float(p.y) * bf2f(x[(size_t)p.x * D + lane]);
    }
    out[(size_t)region * B * D + (size_t)b * D + lane] += 0.25f * acc;
}

// ---------------------------------------------------------------------------
// Output init: raw table gathers (outputs 3..5, exact fp32) and the level-0
// contribution (0.25 * table rows) into outputs 0..2.
// ---------------------------------------------------------------------------
__global__ void gather_init(const float* __restrict__ ut,
                            const float* __restrict__ gt,
                            const int*   __restrict__ ui,
                            const int*   __restrict__ pg,
                            const int*   __restrict__ ng,
                            float*       __restrict__ out) {
    int i = blockIdx.x * blockDim.x + threadIdx.x;    // B*D threads
    if (i >= B * D) return;
    int b = i >> 6, d = i & 63;
    float u = ut[(size_t)ui[b] * D + d];
    float p = gt[(size_t)pg[b] * D + d];
    float n = gt[(size_t)ng[b] * D + d];
    const int S = B * D;
    out[0 * S + i] = 0.25f * u;
    out[1 * S + i] = 0.25f * p;
    out[2 * S + i] = 0.25f * n;
    out[3 * S + i] = u;
    out[4 * S + i] = p;
    out[5 * S + i] = n;
}

// ---------------------------------------------------------------------------
// Per-level accumulation of 0.25 * emb_l (bf16) at the gathered rows
// ---------------------------------------------------------------------------
__global__ void gather_acc(const unsigned short* __restrict__ emb,
                           const int*   __restrict__ ui,
                           const int*   __restrict__ pg,
                           const int*   __restrict__ ng,
                           float*       __restrict__ out) {
    int i = blockIdx.x * blockDim.x + threadIdx.x;    // B*D threads
    if (i >= B * D) return;
    int b = i >> 6, d = i & 63;
    const int S = B * D;
    out[0 * S + i] += 0.25f * bf2f(emb[(size_t)ui[b] * D + d]);
    out[1 * S + i] += 0.25f * bf2f(emb[((size_t)NUM_USER + pg[b]) * D + d]);
    out[2 * S + i] += 0.25f * bf2f(emb[((size_t)NUM_USER + ng[b]) * D + d]);
}

// ---------------------------------------------------------------------------
extern "C" void kernel_launch(void* const* d_in, const int* in_sizes, int n_in,
                              void* d_out, int out_size, void* d_ws, size_t ws_size,
                              hipStream_t stream) {
    const float* ut   = (const float*)d_in[0];
    const float* gt   = (const float*)d_in[1];
    const float* vals = (const float*)d_in[2];
    const int*   rows = (const int*)d_in[3];
    const int*   cols = (const int*)d_in[4];
    const int*   ui   = (const int*)d_in[5];
    const int*   pg   = (const int*)d_in[6];
    const int*   ng   = (const int*)d_in[7];
    float* out = (float*)d_out;

    // --- workspace layout (bf16 embeddings: 16 MB each) ---
    char* ws = (char*)d_ws;
    unsigned short* emb0 = (unsigned short*)ws;  ws += (size_t)NN * D * sizeof(unsigned short); // 32 MB
    unsigned short* emb1 = (unsigned short*)ws;  ws += (size_t)NN * D * sizeof(unsigned short); // 32 MB
    unsigned short* emb2 = (unsigned short*)ws;  ws += (size_t)NN * D * sizeof(unsigned short); // 32 MB
    int2*  pairs   = (int2*)ws;    ws += (size_t)E_EDGES * sizeof(int2);   // 32 MB
    int2*  stage   = (int2*)ws;    ws += (size_t)E_EDGES * sizeof(int2);   // 32 MB
    int*   row_ptr = (int*)ws;     ws += (size_t)(NN + 1) * sizeof(int);
    int*   counts  = (int*)ws;     ws += (size_t)NN * sizeof(int);
    int*   blockSums = (int*)ws;   ws += (size_t)SCAN_BLOCKS * sizeof(int);
    int*   blockOffs = (int*)ws;   ws += (size_t)SCAN_BLOCKS * sizeof(int);
    int*   cursorA   = (int*)ws;   ws += (size_t)NB_BUCKETS * sizeof(int);

    // --- CSR build (once per call; reused for all 3 levels) ---
    hipMemsetAsync(counts, 0, (size_t)NN * sizeof(int), stream);
    hist_kernel<<<(E_EDGES + 255) / 256, 256, 0, stream>>>(rows, counts);
    scan_blocksums<<<SCAN_BLOCKS, 256, 0, stream>>>(counts, blockSums);
    scan_offsets<<<1, 256, 0, stream>>>(blockSums, blockOffs, row_ptr);
    scan_final<<<SCAN_BLOCKS, 256, 0, stream>>>(counts, blockOffs, row_ptr);
    init_bucket_cursors<<<1, 256, 0, stream>>>(row_ptr, cursorA);
    bucket_phaseA<<<(E_EDGES + CHUNK_EDGES - 1) / CHUNK_EDGES, 256, 0, stream>>>(
        rows, cols, vals, cursorA, stage);
    bucket_phaseB<<<NB_BUCKETS, 256, 0, stream>>>(row_ptr, stage, pairs);

    // --- bf16 emb0 + outputs 3..5 + level-0 contribution ---
    {
        long long total4 = (long long)NN * D / 4;
        convert_tables<<<(int)((total4 + 255) / 256), 256, 0, stream>>>(ut, gt, emb0);
    }
    gather_init<<<(B * D + 255) / 256, 256, 0, stream>>>(ut, gt, ui, pg, ng, out);

    // --- propagation: 2 full levels (bf16) + output-sparse final level ---
    const int spmmBlocks = (NN + 3) / 4;   // 4 rows (waves) per 256-thread block
    spmm_pull_bf<<<spmmBlocks, 256, 0, stream>>>(row_ptr, pairs, emb0, emb1);
    gather_acc<<<(B * D + 255) / 256, 256, 0, stream>>>(emb1, ui, pg, ng, out);

    spmm_pull_bf<<<spmmBlocks, 256, 0, stream>>>(row_ptr, pairs, emb1, emb2);
    gather_acc<<<(B * D + 255) / 256, 256, 0, stream>>>(emb2, ui, pg, ng, out);

    // level 3: only the 24576 output rows, fused into the output accumulation
    final_pull<<<(3 * B + 3) / 4, 256, 0, stream>>>(row_ptr, pairs, emb2, ui, pg, ng, out);
}